// Round 3
// baseline (470912.744 us; speedup 1.0000x reference)
//
#include <hip/hip_runtime.h>
#include <stdint.h>

// ---------------------------------------------------------------------------
// RnnSampler: 128 sequential steps of {MLP policy head -> gumbel-max sample ->
// embed -> LSTM cell}. JAX threefry PRNG in PARTITIONABLE mode (verified r2):
//   split:  key_t = threefry2x32(k0,k1, 0, t) -> (o0, o1)
//   bits:   bits[p] = xor(threefry2x32(key, 0, p)), p = flat index
// N=256, E=256, V=32000, steps=128.
// Per step: k_hidden_part (split-K h@W1^T partials) -> k_logits (fused
// relu-sum staging + GEMM + gumbel + argmax partials) -> k_gates_part
// (sample+embed+gates split-K, gate-interleaved Wperm) -> k_gates_fin
// (deterministic partial sum + LSTM update).
// ---------------------------------------------------------------------------

#define STEPS 128
#define NS    256
#define EDIM  256
#define VDIM  32000

__host__ __device__ __forceinline__ void tf2x32(uint32_t k0, uint32_t k1,
                                                uint32_t c0, uint32_t c1,
                                                uint32_t& o0, uint32_t& o1) {
  const uint32_t ks2 = k0 ^ k1 ^ 0x1BD11BDAu;
  uint32_t x0 = c0 + k0, x1 = c1 + k1;
#define TF_R(r) { x0 += x1; x1 = (x1 << (r)) | (x1 >> (32 - (r))); x1 ^= x0; }
  TF_R(13) TF_R(15) TF_R(26) TF_R(6)
  x0 += k1;  x1 += ks2 + 1u;
  TF_R(17) TF_R(29) TF_R(16) TF_R(24)
  x0 += ks2; x1 += k0 + 2u;
  TF_R(13) TF_R(15) TF_R(26) TF_R(6)
  x0 += k0;  x1 += k1 + 3u;
  TF_R(17) TF_R(29) TF_R(16) TF_R(24)
  x0 += k1;  x1 += ks2 + 4u;
  TF_R(13) TF_R(15) TF_R(26) TF_R(6)
  x0 += ks2; x1 += k0 + 5u;
#undef TF_R
  o0 = x0; o1 = x1;
}

// ---------------------------------------------------------------------------
// Hidden split-K partials: hp[kz][r][col] = sum_{k in kz*128..+128} h[r][k]*W1[col][k]
// grid (4 colgrp x 16 rowgrp x 2 kz), 256 thr. No bias/relu here (folded later).
// ---------------------------------------------------------------------------
__global__ __launch_bounds__(256) void k_hidden_part(
    const float* __restrict__ h,    // [256][256]
    const float* __restrict__ W1,   // [512][256]
    float* __restrict__ hp)         // [2][256][512]
{
  __shared__ float At[128][18];     // [k][row], 16 rows
  __shared__ float Bt[16][132];     // [k][col swizzled], 128 cols
  const int tid = threadIdx.x;
  const int tx = tid & 31, ty = tid >> 5;       // cols 4*tx, rows 2*ty
  const int C0 = blockIdx.x * 128;
  const int R0 = blockIdx.y * 16;
  const int koff = blockIdx.z * 128;
  float acc[2][4] = {};

  // stage A once: 16 rows x 128 k, transposed
#pragma unroll
  for (int i = 0; i < 2; i++) {
    int f = tid + 256 * i;          // 0..511
    int r = f >> 5, kq = f & 31;
    float4 v = *(const float4*)(h + (size_t)(R0 + r) * 256 + koff + 4 * kq);
    At[4 * kq + 0][r] = v.x; At[4 * kq + 1][r] = v.y;
    At[4 * kq + 2][r] = v.z; At[4 * kq + 3][r] = v.w;
  }

  for (int ch = 0; ch < 8; ch++) {
    // stage Bt: 128 cols x 16 k, swizzled groups (g' = g ^ ((g>>3)&3))
#pragma unroll
    for (int i = 0; i < 2; i++) {
      int f = tid + 256 * i;        // 0..511
      int c = f >> 2, kq = f & 3;
      float4 w = *(const float4*)(W1 + (size_t)(C0 + c) * 256 + koff + ch * 16 + 4 * kq);
      int g = c >> 2;
      int pos = ((g ^ ((g >> 3) & 3)) << 2) | (c & 3);
      Bt[4 * kq + 0][pos] = w.x; Bt[4 * kq + 1][pos] = w.y;
      Bt[4 * kq + 2][pos] = w.z; Bt[4 * kq + 3][pos] = w.w;
    }
    __syncthreads();
#pragma unroll
    for (int k = 0; k < 16; k++) {
      float af[2], bf[4];
      *(float2*)af = *(const float2*)&At[ch * 16 + k][2 * ty];
      *(float4*)bf = *(const float4*)&Bt[k][(tx ^ ((tx >> 3) & 3)) << 2];
#pragma unroll
      for (int a = 0; a < 2; a++)
#pragma unroll
        for (int j = 0; j < 4; j++)
          acc[a][j] = fmaf(af[a], bf[j], acc[a][j]);
    }
    __syncthreads();
  }
#pragma unroll
  for (int a = 0; a < 2; a++) {
    float4 o = make_float4(acc[a][0], acc[a][1], acc[a][2], acc[a][3]);
    *(float4*)(hp + (size_t)blockIdx.z * 131072 +
               (size_t)(R0 + 2 * ty + a) * 512 + C0 + 4 * tx) = o;
  }
}

// ---------------------------------------------------------------------------
// Logits: A = relu(b1 + hp0 + hp1) staged on the fly; tile 256(M) x 128(N),
// 250 blocks, per-thread 16x8, double-buffered LDS. Fused gumbel + argmax.
// ---------------------------------------------------------------------------
__global__ __launch_bounds__(256, 1) void k_logits(
    const float* __restrict__ hp,   // [2][256][512]
    const float* __restrict__ b1,   // [512]
    const float* __restrict__ W2,   // [32000][512]
    const float* __restrict__ b2,   // [32000]
    unsigned long long* __restrict__ part,  // [256][250]
    uint32_t key0, uint32_t key1)
{
  __shared__ float At[2][16][260];
  __shared__ float Bt[2][16][132];
  __shared__ unsigned long long red[256][17];
  const int tid = threadIdx.x;
  const int tx = tid & 15;        // col group: cols 64*q + 4*tx + j
  const int ty = tid >> 4;        // row group: rows 64*s + 4*ty + a
  const int v0 = blockIdx.x * 128;
  const int r_st = tid >> 2;      // staging base row/col
  const int kq_st = tid & 3;      // staging k-quad
  float acc[4][4][2][4] = {};     // [s][a][q][j]

  // prologue: stage chunk 0 into buffer 0
  {
    float4 b1v = *(const float4*)(b1 + 4 * kq_st);
#pragma unroll
    for (int i = 0; i < 4; i++) {
      int r = r_st + 64 * i;
      float4 p0 = *(const float4*)(hp + (size_t)r * 512 + 4 * kq_st);
      float4 p1 = *(const float4*)(hp + 131072 + (size_t)r * 512 + 4 * kq_st);
      At[0][4 * kq_st + 0][r] = fmaxf(p0.x + p1.x + b1v.x, 0.f);
      At[0][4 * kq_st + 1][r] = fmaxf(p0.y + p1.y + b1v.y, 0.f);
      At[0][4 * kq_st + 2][r] = fmaxf(p0.z + p1.z + b1v.z, 0.f);
      At[0][4 * kq_st + 3][r] = fmaxf(p0.w + p1.w + b1v.w, 0.f);
    }
#pragma unroll
    for (int i = 0; i < 2; i++) {
      int c = r_st + 64 * i;
      float4 w = *(const float4*)(W2 + (size_t)(v0 + c) * 512 + 4 * kq_st);
      Bt[0][4 * kq_st + 0][c] = w.x; Bt[0][4 * kq_st + 1][c] = w.y;
      Bt[0][4 * kq_st + 2][c] = w.z; Bt[0][4 * kq_st + 3][c] = w.w;
    }
  }
  __syncthreads();

  for (int ch = 0; ch < 32; ch++) {
    const int cur = ch & 1, nxt = cur ^ 1;
    float4 p0f[4], p1f[4], b1f, w2f[2];
    if (ch < 31) {  // prefetch next chunk to registers
      const int koff = (ch + 1) * 16;
      b1f = *(const float4*)(b1 + koff + 4 * kq_st);
#pragma unroll
      for (int i = 0; i < 4; i++) {
        int r = r_st + 64 * i;
        p0f[i] = *(const float4*)(hp + (size_t)r * 512 + koff + 4 * kq_st);
        p1f[i] = *(const float4*)(hp + 131072 + (size_t)r * 512 + koff + 4 * kq_st);
      }
#pragma unroll
      for (int i = 0; i < 2; i++) {
        int c = r_st + 64 * i;
        w2f[i] = *(const float4*)(W2 + (size_t)(v0 + c) * 512 + koff + 4 * kq_st);
      }
    }
    // compute 16 k-steps from buf[cur]
#pragma unroll
    for (int k = 0; k < 16; k++) {
      float af[4][4], bf[2][4];
#pragma unroll
      for (int s = 0; s < 4; s++)
        *(float4*)&af[s][0] = *(const float4*)&At[cur][k][s * 64 + 4 * ty];
#pragma unroll
      for (int q = 0; q < 2; q++)
        *(float4*)&bf[q][0] = *(const float4*)&Bt[cur][k][q * 64 + 4 * tx];
#pragma unroll
      for (int s = 0; s < 4; s++)
#pragma unroll
        for (int a = 0; a < 4; a++)
#pragma unroll
          for (int q = 0; q < 2; q++)
#pragma unroll
            for (int j = 0; j < 4; j++)
              acc[s][a][q][j] = fmaf(af[s][a], bf[q][j], acc[s][a][q][j]);
    }
    if (ch < 31) {  // write prefetched regs to buf[nxt]
#pragma unroll
      for (int i = 0; i < 4; i++) {
        int r = r_st + 64 * i;
        At[nxt][4 * kq_st + 0][r] = fmaxf(p0f[i].x + p1f[i].x + b1f.x, 0.f);
        At[nxt][4 * kq_st + 1][r] = fmaxf(p0f[i].y + p1f[i].y + b1f.y, 0.f);
        At[nxt][4 * kq_st + 2][r] = fmaxf(p0f[i].z + p1f[i].z + b1f.z, 0.f);
        At[nxt][4 * kq_st + 3][r] = fmaxf(p0f[i].w + p1f[i].w + b1f.w, 0.f);
      }
#pragma unroll
      for (int i = 0; i < 2; i++) {
        int c = r_st + 64 * i;
        Bt[nxt][4 * kq_st + 0][c] = w2f[i].x; Bt[nxt][4 * kq_st + 1][c] = w2f[i].y;
        Bt[nxt][4 * kq_st + 2][c] = w2f[i].z; Bt[nxt][4 * kq_st + 3][c] = w2f[i].w;
      }
    }
    __syncthreads();
  }

  // epilogue: gumbel + per-row argmax over this block's 128 cols
  float bcol[2][4];
#pragma unroll
  for (int q = 0; q < 2; q++)
#pragma unroll
    for (int j = 0; j < 4; j++)
      bcol[q][j] = b2[v0 + 64 * q + 4 * tx + j];

#pragma unroll
  for (int s = 0; s < 4; s++)
#pragma unroll
    for (int a = 0; a < 4; a++) {
      const int r = s * 64 + 4 * ty + a;
      unsigned long long best = 0ull;
#pragma unroll
      for (int q = 0; q < 2; q++)
#pragma unroll
        for (int j = 0; j < 4; j++) {
          const int v = v0 + 64 * q + 4 * tx + j;
          const uint32_t p = (uint32_t)r * 32000u + (uint32_t)v;
          uint32_t o0, o1;
          tf2x32(key0, key1, 0u, p, o0, o1);
          const uint32_t bits = o0 ^ o1;
          float f = __uint_as_float((bits >> 9) | 0x3f800000u) - 1.0f;
          float u = fmaxf(f, 1.17549435e-38f);
          float g = -logf(-logf(u));
          float val = acc[s][a][q][j] + bcol[q][j] + g;
          uint32_t uv = __float_as_uint(val);
          uv = (uv & 0x80000000u) ? ~uv : (uv | 0x80000000u);
          unsigned long long pk =
              ((unsigned long long)uv << 32) |
              (unsigned long long)(0xFFFFFFFFu - (uint32_t)v);
          best = (pk > best) ? pk : best;
        }
      red[r][tx] = best;
    }
  __syncthreads();
  {
    unsigned long long best = 0ull;
#pragma unroll
    for (int i = 0; i < 16; i++) {
      unsigned long long x = red[tid][i];
      best = (x > best) ? x : best;
    }
    part[(size_t)tid * 250 + blockIdx.x] = best;
  }
}

// ---------------------------------------------------------------------------
// Gates split-K with fused sampling + embedding gather.
// grid (16 rowgrp x 4 colgrp x 4 ksplit), 256 thr.
// Wperm row 4e+g = [W_ih|W_hh] row g*256+e, so each col quad = one gate quad.
// pp[ks][r][c] partials.
// ---------------------------------------------------------------------------
__global__ __launch_bounds__(256) void k_gates_part(
    const unsigned long long* __restrict__ part,  // [256][250]
    const float* __restrict__ emb,   // [32000][256]
    const float* __restrict__ h,     // [256][256]
    const float* __restrict__ Wp,    // [1024][512]
    float* __restrict__ pp,          // [4][256][1024]
    int* __restrict__ out, int t)
{
  __shared__ float At[128][20];                 // [k][row], 16 rows
  __shared__ float Bt[16][260];                 // [k][col swizzled], 256 cols
  __shared__ unsigned long long red2[16][17];
  __shared__ int tok_s[16];
  const int tid = threadIdx.x;
  const int tx = tid & 63, ty = tid >> 6;       // cols 4*tx, rows 4*ty
  const int R0 = blockIdx.x * 16;
  const int C0 = blockIdx.y * 256;
  const int bz = blockIdx.z;                    // k-range bz*128..+128
  float acc[4][4] = {};

  // phase A: token reduce for 16 rows
  {
    const int rw = tid >> 4, il = tid & 15;
    unsigned long long b = 0ull;
    for (int i = il; i < 250; i += 16) {
      unsigned long long x = part[(size_t)(R0 + rw) * 250 + i];
      b = (x > b) ? x : b;
    }
    red2[rw][il] = b;
  }
  __syncthreads();
  if (tid < 16) {
    unsigned long long b = 0ull;
#pragma unroll
    for (int i = 0; i < 16; i++) {
      unsigned long long x = red2[tid][i];
      b = (x > b) ? x : b;
    }
    int tok = (int)(0xFFFFFFFFu - (uint32_t)(b & 0xFFFFFFFFu));
    tok_s[tid] = tok;
    if (blockIdx.y == 0 && blockIdx.z == 0)
      out[(size_t)(R0 + tid) * STEPS + t] = tok;
  }
  __syncthreads();

  // phase B: stage A (16 rows x 128 k): x (embed) for bz<2, h for bz>=2
#pragma unroll
  for (int i = 0; i < 2; i++) {
    int f = tid + 256 * i;   // 0..511
    int r = f >> 5, kq = f & 31;
    const float* src = (bz < 2)
        ? (emb + (size_t)tok_s[r] * 256 + bz * 128 + 4 * kq)
        : (h + (size_t)(R0 + r) * 256 + (bz - 2) * 128 + 4 * kq);
    float4 v = *(const float4*)src;
    At[4 * kq + 0][r] = v.x; At[4 * kq + 1][r] = v.y;
    At[4 * kq + 2][r] = v.z; At[4 * kq + 3][r] = v.w;
  }

  // phase C: K-loop over 8 chunks of 16
  for (int ch = 0; ch < 8; ch++) {
#pragma unroll
    for (int i = 0; i < 4; i++) {
      int f = tid + 256 * i;  // 0..1023
      int c = f >> 2, kq = f & 3;
      float4 w = *(const float4*)(Wp + (size_t)(C0 + c) * 512 + bz * 128 + ch * 16 + 4 * kq);
      int g = c >> 2;
      int pos = ((g ^ ((g >> 3) & 7)) << 2) | (c & 3);
      Bt[4 * kq + 0][pos] = w.x; Bt[4 * kq + 1][pos] = w.y;
      Bt[4 * kq + 2][pos] = w.z; Bt[4 * kq + 3][pos] = w.w;
    }
    __syncthreads();
#pragma unroll
    for (int k = 0; k < 16; k++) {
      float af[4], bf[4];
      *(float4*)af = *(const float4*)&At[ch * 16 + k][4 * ty];
      *(float4*)bf = *(const float4*)&Bt[k][(tx ^ ((tx >> 3) & 7)) << 2];
#pragma unroll
      for (int a = 0; a < 4; a++)
#pragma unroll
        for (int j = 0; j < 4; j++)
          acc[a][j] = fmaf(af[a], bf[j], acc[a][j]);
    }
    __syncthreads();
  }
#pragma unroll
  for (int a = 0; a < 4; a++) {
    float4 o = make_float4(acc[a][0], acc[a][1], acc[a][2], acc[a][3]);
    *(float4*)(pp + (size_t)bz * 262144 +
               (size_t)(R0 + 4 * ty + a) * 1024 + C0 + 4 * tx) = o;
  }
}

// Deterministic partial reduce + LSTM update. grid 256 (rows) x 256 thr (units)
__global__ __launch_bounds__(256) void k_gates_fin(
    const float* __restrict__ pp,      // [4][256][1024]
    const float* __restrict__ bcatp,   // [1024]
    float* __restrict__ c, float* __restrict__ h)
{
  const int r = blockIdx.x, u = threadIdx.x;
  const size_t off = (size_t)r * 1024 + 4 * u;
  float4 s0 = *(const float4*)(pp + off);
  float4 s1 = *(const float4*)(pp + 262144 + off);
  float4 s2 = *(const float4*)(pp + 524288 + off);
  float4 s3 = *(const float4*)(pp + 786432 + off);
  float4 bb = *(const float4*)(bcatp + 4 * u);
  float gi = ((s0.x + s1.x) + s2.x) + s3.x + bb.x;
  float gf = ((s0.y + s1.y) + s2.y) + s3.y + bb.y;
  float gg = ((s0.z + s1.z) + s2.z) + s3.z + bb.z;
  float go = ((s0.w + s1.w) + s2.w) + s3.w + bb.w;
  float si = 1.0f / (1.0f + expf(-gi));
  float sf = 1.0f / (1.0f + expf(-gf));
  float so = 1.0f / (1.0f + expf(-go));
  float cv = sf * c[(size_t)r * 256 + u] + si * tanhf(gg);
  c[(size_t)r * 256 + u] = cv;
  h[(size_t)r * 256 + u] = so * tanhf(cv);
}

__global__ __launch_bounds__(256) void k_init(
    float* __restrict__ h, float* __restrict__ c,
    const float* __restrict__ init_h)
{
  const int n = blockIdx.x, e = threadIdx.x;
  const float v = init_h[e];
  h[(size_t)n * 256 + e] = v;
  c[(size_t)n * 256 + e] = v;
}

// Wperm[4e+g][:] = [W_ih | W_hh][g*256+e][:]; bcatp[4e+g] = b_ih+b_hh
__global__ __launch_bounds__(256) void k_prep(
    float* __restrict__ Wp, float* __restrict__ bcatp,
    const float* __restrict__ W_ih, const float* __restrict__ W_hh,
    const float* __restrict__ b_ih, const float* __restrict__ b_hh)
{
  const int q = blockIdx.x, k = threadIdx.x;
  const int e = q >> 2, g = q & 3;
  const int src = g * 256 + e;
  Wp[(size_t)q * 512 + k]       = W_ih[(size_t)src * 256 + k];
  Wp[(size_t)q * 512 + 256 + k] = W_hh[(size_t)src * 256 + k];
  if (k == 0) bcatp[q] = b_ih[src] + b_hh[src];
}

extern "C" void kernel_launch(void* const* d_in, const int* in_sizes, int n_in,
                              void* d_out, int out_size, void* d_ws, size_t ws_size,
                              hipStream_t stream) {
  const float* init_h      = (const float*)d_in[2];
  const float* token_embed = (const float*)d_in[3];
  const float* W_ih        = (const float*)d_in[4];
  const float* W_hh        = (const float*)d_in[5];
  const float* b_ih        = (const float*)d_in[6];
  const float* b_hh        = (const float*)d_in[7];
  const float* W1          = (const float*)d_in[8];
  const float* b1          = (const float*)d_in[9];
  const float* W2          = (const float*)d_in[10];
  const float* b2          = (const float*)d_in[11];
  int* out = (int*)d_out;

  // workspace carve (bytes):
  char* ws = (char*)d_ws;
  float* h     = (float*)(ws + 0);        //   256 KB [256][256]
  float* c     = (float*)(ws + 262144);   //   256 KB [256][256]
  float* Wp    = (float*)(ws + 524288);   //     2 MB [1024][512]
  float* bcatp = (float*)(ws + 2621440);  //     4 KB [1024]
  unsigned long long* part = (unsigned long long*)(ws + 2625536); // 512000 B
  float* hp    = (float*)(ws + 3137536);  //     1 MB [2][256][512]
  float* pp    = (float*)(ws + 4186112);  //     4 MB [4][256][1024]
  // total 8380416 B

  // host JAX key schedule (partitionable split, verified round 2)
  uint32_t k0[STEPS], k1[STEPS];
  for (uint32_t t = 0; t < STEPS; t++) tf2x32(0u, 42u, 0u, t, k0[t], k1[t]);

  k_init<<<NS, 256, 0, stream>>>(h, c, init_h);
  k_prep<<<1024, 256, 0, stream>>>(Wp, bcatp, W_ih, W_hh, b_ih, b_hh);

  for (int t = 0; t < STEPS; t++) {
    k_hidden_part<<<dim3(4, 16, 2), 256, 0, stream>>>(h, W1, hp);
    k_logits<<<250, 256, 0, stream>>>(hp, b1, W2, b2, part, k0[t], k1[t]);
    k_gates_part<<<dim3(16, 4, 4), 256, 0, stream>>>(part, token_embed, h, Wp, pp, out, t);
    k_gates_fin<<<NS, 256, 0, stream>>>(pp, bcatp, c, h);
  }
}

// Round 4
// 21058.076 us; speedup vs baseline: 22.3626x; 22.3626x over previous
//
#include <hip/hip_runtime.h>
#include <stdint.h>

// ---------------------------------------------------------------------------
// RnnSampler: 128 sequential steps of {MLP policy head -> gumbel-max sample ->
// embed -> LSTM cell}. JAX threefry PRNG in PARTITIONABLE mode (verified r2):
//   split:  key_t = threefry2x32(k0,k1, 0, t) -> (o0, o1)
//   bits:   bits[p] = xor(threefry2x32(key, 0, p)), p = flat index
// N=256, E=256, V=32000, steps=128.
// Structure = round-2 (measured 21.6 ms) with ONE change: k_logits is now a
// single pass (250 blocks x 512 thr, M=256 x N=128 tile) instead of two
// passes (500 blocks). Per-thread shape (64 acc, 4 b128 + 64 FMA per k-step)
// identical to the measured-good round-2 kernel. LDS 59.9 KB, VGPR ~130.
// ---------------------------------------------------------------------------

#define STEPS 128
#define NS    256
#define EDIM  256
#define VDIM  32000

// Threefry-2x32, 20 rounds (Random123 / JAX-compatible)
__host__ __device__ __forceinline__ void tf2x32(uint32_t k0, uint32_t k1,
                                                uint32_t c0, uint32_t c1,
                                                uint32_t& o0, uint32_t& o1) {
  const uint32_t ks2 = k0 ^ k1 ^ 0x1BD11BDAu;
  uint32_t x0 = c0 + k0, x1 = c1 + k1;
#define TF_R(r) { x0 += x1; x1 = (x1 << (r)) | (x1 >> (32 - (r))); x1 ^= x0; }
  TF_R(13) TF_R(15) TF_R(26) TF_R(6)
  x0 += k1;  x1 += ks2 + 1u;
  TF_R(17) TF_R(29) TF_R(16) TF_R(24)
  x0 += ks2; x1 += k0 + 2u;
  TF_R(13) TF_R(15) TF_R(26) TF_R(6)
  x0 += k0;  x1 += k1 + 3u;
  TF_R(17) TF_R(29) TF_R(16) TF_R(24)
  x0 += k1;  x1 += ks2 + 4u;
  TF_R(13) TF_R(15) TF_R(26) TF_R(6)
  x0 += ks2; x1 += k0 + 5u;
#undef TF_R
  o0 = x0; o1 = x1;
}

// ---------------------------------------------------------------------------
// Generic fp32 GEMM: C[M,N] = act(A[M,K] * B[N,K]^T + bias), tiles TILExTILE.
// (verbatim round 2)
// ---------------------------------------------------------------------------
template<int TILE, bool RELU>
__global__ __launch_bounds__(256) void k_gemm(
    const float* __restrict__ A, int lda,
    const float* __restrict__ B, int ldb,
    const float* __restrict__ bias,
    float* __restrict__ C, int ldc, int K)
{
  constexpr int TM = TILE / 16;
  __shared__ float At[16][TILE + 4];
  __shared__ float Bt[16][TILE + 4];
  const int tid = threadIdx.x;
  const int tx = tid & 15, ty = tid >> 4;
  const int n0 = blockIdx.y * TILE;   // row (M) offset
  const int v0 = blockIdx.x * TILE;   // col (N) offset
  float acc[TM][TM] = {};

  for (int kk = 0; kk < K; kk += 16) {
#pragma unroll
    for (int i = 0; i < TILE / 64; i++) {
      int id = tid * (TILE / 64) + i;
      int r = id >> 2, c4 = (id & 3) << 2;
      float4 a = *(const float4*)(A + (size_t)(n0 + r) * lda + kk + c4);
      float4 b = *(const float4*)(B + (size_t)(v0 + r) * ldb + kk + c4);
      At[c4 + 0][r] = a.x; At[c4 + 1][r] = a.y; At[c4 + 2][r] = a.z; At[c4 + 3][r] = a.w;
      Bt[c4 + 0][r] = b.x; Bt[c4 + 1][r] = b.y; Bt[c4 + 2][r] = b.z; Bt[c4 + 3][r] = b.w;
    }
    __syncthreads();
#pragma unroll
    for (int k = 0; k < 16; k++) {
      float af[TM], bf[TM];
#pragma unroll
      for (int m = 0; m < TM; m += 4) {
        *(float4*)&af[m] = *(const float4*)&At[k][ty * TM + m];
        *(float4*)&bf[m] = *(const float4*)&Bt[k][tx * TM + m];
      }
#pragma unroll
      for (int a = 0; a < TM; a++)
#pragma unroll
        for (int b = 0; b < TM; b++)
          acc[a][b] = fmaf(af[a], bf[b], acc[a][b]);
    }
    __syncthreads();
  }
#pragma unroll
  for (int a = 0; a < TM; a++) {
    int r = n0 + ty * TM + a;
#pragma unroll
    for (int b = 0; b < TM; b++) {
      int v = v0 + tx * TM + b;
      float x = acc[a][b] + bias[v];
      if (RELU) x = fmaxf(x, 0.0f);
      C[(size_t)r * ldc + v] = x;
    }
  }
}

// ---------------------------------------------------------------------------
// Logits GEMM, ONE pass: 250 blocks x 512 threads, tile M=256 x N=128, K=512.
// Per-thread: rows 8*ty+a (a<8), cols v0 + q*64 + 4*tx + j (q<2, j<4) -> 64 acc.
// Single-buffered LDS (round-2 style). Fused gumbel + per-row argmax partials:
// part[row*250 + blockIdx.x] = packed (orderedFloat, ~idx).
// ---------------------------------------------------------------------------
__global__ __launch_bounds__(512, 2) void k_logits(
    const float* __restrict__ A,      // hidden [256][512]
    const float* __restrict__ B,      // W2 [32000][512]
    const float* __restrict__ bias,   // b2 [32000]
    unsigned long long* __restrict__ part,  // [256][250]
    uint32_t key0, uint32_t key1)
{
  __shared__ float At[16][260];
  __shared__ float Bt[16][132];
  __shared__ unsigned long long red[256][17];
  const int tid = threadIdx.x;
  const int tx = tid & 15;        // col: v0 + q*64 + 4*tx + j
  const int ty = tid >> 4;        // rows 8*ty .. 8*ty+7   (ty 0..31)
  const int v0 = blockIdx.x * 128;
  float acc[8][2][4] = {};        // [a][q][j]

  for (int kk = 0; kk < 512; kk += 16) {
    // stage A: 16k x 256 rows (1024 float4 by 512 thr, 2 each)
#pragma unroll
    for (int i = 0; i < 2; i++) {
      int f = tid * 2 + i;                 // 0..1023
      int r = f >> 2, kq = f & 3;
      float4 a = *(const float4*)(A + (size_t)r * 512 + kk + 4 * kq);
      At[4 * kq + 0][r] = a.x; At[4 * kq + 1][r] = a.y;
      At[4 * kq + 2][r] = a.z; At[4 * kq + 3][r] = a.w;
    }
    // stage B: 16k x 128 cols (512 float4 by 512 thr, 1 each)
    {
      int c = tid >> 2, kq = tid & 3;
      float4 b = *(const float4*)(B + (size_t)(v0 + c) * 512 + kk + 4 * kq);
      Bt[4 * kq + 0][c] = b.x; Bt[4 * kq + 1][c] = b.y;
      Bt[4 * kq + 2][c] = b.z; Bt[4 * kq + 3][c] = b.w;
    }
    __syncthreads();
#pragma unroll
    for (int k = 0; k < 16; k++) {
      float af[8], bf[2][4];
      *(float4*)&af[0] = *(const float4*)&At[k][8 * ty];
      *(float4*)&af[4] = *(const float4*)&At[k][8 * ty + 4];
      *(float4*)&bf[0][0] = *(const float4*)&Bt[k][4 * tx];
      *(float4*)&bf[1][0] = *(const float4*)&Bt[k][64 + 4 * tx];
#pragma unroll
      for (int a = 0; a < 8; a++)
#pragma unroll
        for (int q = 0; q < 2; q++)
#pragma unroll
          for (int j = 0; j < 4; j++)
            acc[a][q][j] = fmaf(af[a], bf[q][j], acc[a][q][j]);
    }
    __syncthreads();
  }

  // epilogue: gumbel + per-row argmax over this block's 128 cols
#pragma unroll
  for (int a = 0; a < 8; a++) {
    const int r = 8 * ty + a;
    unsigned long long best = 0ull;
#pragma unroll
    for (int q = 0; q < 2; q++)
#pragma unroll
      for (int j = 0; j < 4; j++) {
        const int v = v0 + 64 * q + 4 * tx + j;
        const uint32_t p = (uint32_t)r * 32000u + (uint32_t)v;
        uint32_t o0, o1;
        tf2x32(key0, key1, 0u, p, o0, o1);
        const uint32_t bits = o0 ^ o1;
        // JAX uniform: bitcast(bits>>9 | 0x3f800000) - 1, clamped to tiny
        float f = __uint_as_float((bits >> 9) | 0x3f800000u) - 1.0f;
        float u = fmaxf(f, 1.17549435e-38f);
        float g = -logf(-logf(u));
        float val = acc[a][q][j] + bias[v] + g;
        uint32_t uv = __float_as_uint(val);
        uv = (uv & 0x80000000u) ? ~uv : (uv | 0x80000000u);  // order-preserving
        unsigned long long pk =
            ((unsigned long long)uv << 32) |
            (unsigned long long)(0xFFFFFFFFu - (uint32_t)v);  // tie -> lowest v
        best = (pk > best) ? pk : best;
      }
    red[r][tx] = best;
  }
  __syncthreads();
  if (tid < 256) {
    unsigned long long best = 0ull;
#pragma unroll
    for (int i = 0; i < 16; i++) {
      unsigned long long x = red[tid][i];
      best = (x > best) ? x : best;
    }
    part[(size_t)tid * 250 + blockIdx.x] = best;
  }
}

// Per-row final reduction over 250 partials -> token; write out + gather embed
__global__ __launch_bounds__(256) void k_sample(
    const unsigned long long* __restrict__ part,
    const float* __restrict__ token_embed,
    int* __restrict__ out, float* __restrict__ xh, int t)
{
  __shared__ unsigned long long sm[256];
  const int row = blockIdx.x, tid = threadIdx.x;
  sm[tid] = (tid < 250) ? part[(size_t)row * 250 + tid] : 0ull;
  __syncthreads();
  for (int s = 128; s > 0; s >>= 1) {
    if (tid < s) {
      unsigned long long o = sm[tid + s];
      if (o > sm[tid]) sm[tid] = o;
    }
    __syncthreads();
  }
  const int token = (int)(0xFFFFFFFFu - (uint32_t)(sm[0] & 0xFFFFFFFFu));
  if (tid == 0) out[(size_t)row * STEPS + t] = token;
  // gather embedding row into xh[:, 0:256]
  xh[(size_t)row * 512 + tid] = token_embed[(size_t)token * EDIM + tid];
}

// LSTM elementwise update: gates [256][1024] (i|f|g|o), c [256][256],
// h written to xh[:, 256:512]
__global__ __launch_bounds__(256) void k_update(
    const float* __restrict__ gates, float* __restrict__ c,
    float* __restrict__ xh)
{
  const int n = blockIdx.x, e = threadIdx.x;
  const float* g = gates + (size_t)n * 1024;
  const float gi = g[e], gf = g[256 + e], gg = g[512 + e], go = g[768 + e];
  const float si = 1.0f / (1.0f + expf(-gi));
  const float sf = 1.0f / (1.0f + expf(-gf));
  const float so = 1.0f / (1.0f + expf(-go));
  float cv = sf * c[(size_t)n * 256 + e] + si * tanhf(gg);
  c[(size_t)n * 256 + e] = cv;
  xh[(size_t)n * 512 + 256 + e] = so * tanhf(cv);
}

__global__ __launch_bounds__(256) void k_init(
    float* __restrict__ xh, float* __restrict__ c,
    const float* __restrict__ init_h)
{
  const int n = blockIdx.x, e = threadIdx.x;
  const float v = init_h[e];
  xh[(size_t)n * 512 + 256 + e] = v;
  c[(size_t)n * 256 + e] = v;
}

// Build Wcat = [W_ih | W_hh] (1024 x 512) and bcat = b_ih + b_hh
__global__ __launch_bounds__(256) void k_prep(
    float* __restrict__ Wcat, float* __restrict__ bcat,
    const float* __restrict__ W_ih, const float* __restrict__ W_hh,
    const float* __restrict__ b_ih, const float* __restrict__ b_hh)
{
  const int q = blockIdx.x, e = threadIdx.x;
  Wcat[(size_t)q * 512 + e]       = W_ih[(size_t)q * 256 + e];
  Wcat[(size_t)q * 512 + 256 + e] = W_hh[(size_t)q * 256 + e];
  if (e == 0) bcat[q] = b_ih[q] + b_hh[q];
}

extern "C" void kernel_launch(void* const* d_in, const int* in_sizes, int n_in,
                              void* d_out, int out_size, void* d_ws, size_t ws_size,
                              hipStream_t stream) {
  const float* init_h      = (const float*)d_in[2];
  const float* token_embed = (const float*)d_in[3];
  const float* W_ih        = (const float*)d_in[4];
  const float* W_hh        = (const float*)d_in[5];
  const float* b_ih        = (const float*)d_in[6];
  const float* b_hh        = (const float*)d_in[7];
  const float* W1          = (const float*)d_in[8];
  const float* b1          = (const float*)d_in[9];
  const float* W2          = (const float*)d_in[10];
  const float* b2          = (const float*)d_in[11];
  int* out = (int*)d_out;

  // workspace carve (all offsets 16B-aligned) — identical to round 2
  char* ws = (char*)d_ws;
  float* xh      = (float*)(ws + 0);            // [256][512]  x | h
  float* c       = (float*)(ws + 524288);       // [256][256]
  float* hidden  = (float*)(ws + 786432);       // [256][512]
  float* gates   = (float*)(ws + 1310720);      // [256][1024]
  float* Wcat    = (float*)(ws + 2359296);      // [1024][512]
  float* bcat    = (float*)(ws + 4456448);      // [1024]
  unsigned long long* part = (unsigned long long*)(ws + 4460544); // [256][250]

  // Host-side JAX key schedule, PARTITIONABLE (foldlike) split:
  // keys[t] = threefry2x32(0, 42, c0=0, c1=t) -> (o0, o1)
  uint32_t k0[STEPS], k1[STEPS];
  for (uint32_t t = 0; t < STEPS; t++) tf2x32(0u, 42u, 0u, t, k0[t], k1[t]);

  k_init<<<NS, 256, 0, stream>>>(xh, c, init_h);
  k_prep<<<1024, 256, 0, stream>>>(Wcat, bcat, W_ih, W_hh, b_ih, b_hh);

  for (int t = 0; t < STEPS; t++) {
    // hidden = relu(h @ W1^T + b1): M=256, N=512, K=256
    k_gemm<64, true><<<dim3(8, 4), 256, 0, stream>>>(
        xh + 256, 512, W1, 256, b1, hidden, 512, 256);
    // logits + gumbel + argmax partials: M=256, N=32000, K=512 (ONE pass)
    k_logits<<<250, 512, 0, stream>>>(
        hidden, W2, b2, part, k0[t], k1[t]);
    // reduce partials -> token -> out + embedding gather into xh[:,0:256]
    k_sample<<<NS, 256, 0, stream>>>(part, token_embed, out, xh, t);
    // gates = [x|h] @ Wcat^T + bcat: M=256, N=1024, K=512
    k_gemm<64, false><<<dim3(16, 4), 256, 0, stream>>>(
        xh, 512, Wcat, 512, bcat, gates, 1024, 512);
    // LSTM state update
    k_update<<<NS, 256, 0, stream>>>(gates, c, xh);
  }
}

// Round 5
// 20780.862 us; speedup vs baseline: 22.6609x; 1.0133x over previous
//
#include <hip/hip_runtime.h>
#include <stdint.h>

// ---------------------------------------------------------------------------
// RnnSampler: 128 sequential steps of {MLP policy head -> gumbel-max sample ->
// embed -> LSTM cell}. JAX threefry PRNG in PARTITIONABLE mode (verified r2).
// N=256, E=256, V=32000, steps=128.
// Structure (r5): 3 kernels/step:
//   k_logits  : M=256 x N=32000 GEMM + gumbel + per-row argmax partials
//               (r4 main loop verbatim; epilogue now shfl-reduce, no LDS tree)
//   k_gates   : partial-reduce -> token -> embed gather -> gates GEMM (full K)
//               -> fused LSTM update (gate-interleaved Wp permutation)
//   k_hidden  : relu(h @ W1^T + b1) with register-prefetch staging
// h double-buffered across steps (gates reads h_cur, writes h_nxt).
// ---------------------------------------------------------------------------

#define STEPS 128
#define NS    256
#define EDIM  256
#define VDIM  32000

// Threefry-2x32, 20 rounds (Random123 / JAX-compatible)
__host__ __device__ __forceinline__ void tf2x32(uint32_t k0, uint32_t k1,
                                                uint32_t c0, uint32_t c1,
                                                uint32_t& o0, uint32_t& o1) {
  const uint32_t ks2 = k0 ^ k1 ^ 0x1BD11BDAu;
  uint32_t x0 = c0 + k0, x1 = c1 + k1;
#define TF_R(r) { x0 += x1; x1 = (x1 << (r)) | (x1 >> (32 - (r))); x1 ^= x0; }
  TF_R(13) TF_R(15) TF_R(26) TF_R(6)
  x0 += k1;  x1 += ks2 + 1u;
  TF_R(17) TF_R(29) TF_R(16) TF_R(24)
  x0 += ks2; x1 += k0 + 2u;
  TF_R(13) TF_R(15) TF_R(26) TF_R(6)
  x0 += k0;  x1 += k1 + 3u;
  TF_R(17) TF_R(29) TF_R(16) TF_R(24)
  x0 += k1;  x1 += ks2 + 4u;
  TF_R(13) TF_R(15) TF_R(26) TF_R(6)
  x0 += ks2; x1 += k0 + 5u;
#undef TF_R
  o0 = x0; o1 = x1;
}

__device__ __forceinline__ unsigned long long shflx64(unsigned long long v, int m) {
  int lo = __shfl_xor((int)(uint32_t)v, m, 64);
  int hi = __shfl_xor((int)(uint32_t)(v >> 32), m, 64);
  return ((unsigned long long)(uint32_t)hi << 32) | (unsigned long long)(uint32_t)lo;
}

// ---------------------------------------------------------------------------
// k_hidden: C[M=256,N=512] = relu(A[256,256] * W1[512,256]^T + b1)
// 64x64 tiles, grid (8 colgrps, 4 rowgrps), 256 thr. Register-prefetch staging.
// ---------------------------------------------------------------------------
__global__ __launch_bounds__(256) void k_hidden(
    const float* __restrict__ A,    // h [256][256]
    const float* __restrict__ B,    // W1 [512][256]
    const float* __restrict__ bias, // b1 [512]
    float* __restrict__ C)          // hidden [256][512]
{
  __shared__ float At[16][68];
  __shared__ float Bt[16][68];
  const int tid = threadIdx.x;
  const int tx = tid & 15, ty = tid >> 4;
  const int n0 = blockIdx.y * 64;   // rows
  const int v0 = blockIdx.x * 64;   // cols
  const int r_st = tid >> 2, c4_st = (tid & 3) << 2;
  float acc[4][4] = {};

  // stage chunk 0
  {
    float4 a = *(const float4*)(A + (size_t)(n0 + r_st) * 256 + c4_st);
    float4 b = *(const float4*)(B + (size_t)(v0 + r_st) * 256 + c4_st);
    At[c4_st + 0][r_st] = a.x; At[c4_st + 1][r_st] = a.y;
    At[c4_st + 2][r_st] = a.z; At[c4_st + 3][r_st] = a.w;
    Bt[c4_st + 0][r_st] = b.x; Bt[c4_st + 1][r_st] = b.y;
    Bt[c4_st + 2][r_st] = b.z; Bt[c4_st + 3][r_st] = b.w;
  }
  __syncthreads();

  for (int kk = 0; kk < 256; kk += 16) {
    float4 pa, pb;
    if (kk < 240) {
      pa = *(const float4*)(A + (size_t)(n0 + r_st) * 256 + kk + 16 + c4_st);
      pb = *(const float4*)(B + (size_t)(v0 + r_st) * 256 + kk + 16 + c4_st);
    }
#pragma unroll
    for (int k = 0; k < 16; k++) {
      float af[4], bf[4];
      *(float4*)af = *(const float4*)&At[k][ty * 4];
      *(float4*)bf = *(const float4*)&Bt[k][tx * 4];
#pragma unroll
      for (int a = 0; a < 4; a++)
#pragma unroll
        for (int b = 0; b < 4; b++)
          acc[a][b] = fmaf(af[a], bf[b], acc[a][b]);
    }
    __syncthreads();
    if (kk < 240) {
      At[c4_st + 0][r_st] = pa.x; At[c4_st + 1][r_st] = pa.y;
      At[c4_st + 2][r_st] = pa.z; At[c4_st + 3][r_st] = pa.w;
      Bt[c4_st + 0][r_st] = pb.x; Bt[c4_st + 1][r_st] = pb.y;
      Bt[c4_st + 2][r_st] = pb.z; Bt[c4_st + 3][r_st] = pb.w;
    }
    __syncthreads();
  }
#pragma unroll
  for (int a = 0; a < 4; a++) {
    int r = n0 + ty * 4 + a;
#pragma unroll
    for (int b = 0; b < 4; b++) {
      int v = v0 + tx * 4 + b;
      C[(size_t)r * 512 + v] = fmaxf(acc[a][b] + bias[v], 0.0f);
    }
  }
}

// ---------------------------------------------------------------------------
// k_logits: 250 blocks x 512 thr, tile M=256 x N=128, K=512. Main loop = r4
// verbatim. Epilogue: gumbel + thread-local argmax + 16-lane shfl reduce.
// ---------------------------------------------------------------------------
__global__ __launch_bounds__(512, 2) void k_logits(
    const float* __restrict__ A,      // hidden [256][512]
    const float* __restrict__ B,      // W2 [32000][512]
    const float* __restrict__ bias,   // b2 [32000]
    unsigned long long* __restrict__ part,  // [256][250]
    uint32_t key0, uint32_t key1)
{
  __shared__ float At[16][260];
  __shared__ float Bt[16][132];
  const int tid = threadIdx.x;
  const int tx = tid & 15;        // col: v0 + q*64 + 4*tx + j
  const int ty = tid >> 4;        // rows 8*ty .. 8*ty+7   (ty 0..31)
  const int v0 = blockIdx.x * 128;
  float acc[8][2][4] = {};        // [a][q][j]

  for (int kk = 0; kk < 512; kk += 16) {
#pragma unroll
    for (int i = 0; i < 2; i++) {
      int f = tid * 2 + i;                 // 0..1023
      int r = f >> 2, kq = f & 3;
      float4 a = *(const float4*)(A + (size_t)r * 512 + kk + 4 * kq);
      At[4 * kq + 0][r] = a.x; At[4 * kq + 1][r] = a.y;
      At[4 * kq + 2][r] = a.z; At[4 * kq + 3][r] = a.w;
    }
    {
      int c = tid >> 2, kq = tid & 3;
      float4 b = *(const float4*)(B + (size_t)(v0 + c) * 512 + kk + 4 * kq);
      Bt[4 * kq + 0][c] = b.x; Bt[4 * kq + 1][c] = b.y;
      Bt[4 * kq + 2][c] = b.z; Bt[4 * kq + 3][c] = b.w;
    }
    __syncthreads();
#pragma unroll
    for (int k = 0; k < 16; k++) {
      float af[8], bf[2][4];
      *(float4*)&af[0] = *(const float4*)&At[k][8 * ty];
      *(float4*)&af[4] = *(const float4*)&At[k][8 * ty + 4];
      *(float4*)&bf[0][0] = *(const float4*)&Bt[k][4 * tx];
      *(float4*)&bf[1][0] = *(const float4*)&Bt[k][64 + 4 * tx];
#pragma unroll
      for (int a = 0; a < 8; a++)
#pragma unroll
        for (int q = 0; q < 2; q++)
#pragma unroll
          for (int j = 0; j < 4; j++)
            acc[a][q][j] = fmaf(af[a], bf[q][j], acc[a][q][j]);
    }
    __syncthreads();
  }

  // epilogue: gumbel + per-row argmax; reduce across the 16 tx lanes via shfl
#pragma unroll
  for (int a = 0; a < 8; a++) {
    const int r = 8 * ty + a;
    unsigned long long best = 0ull;
#pragma unroll
    for (int q = 0; q < 2; q++)
#pragma unroll
      for (int j = 0; j < 4; j++) {
        const int v = v0 + 64 * q + 4 * tx + j;
        const uint32_t p = (uint32_t)r * 32000u + (uint32_t)v;
        uint32_t o0, o1;
        tf2x32(key0, key1, 0u, p, o0, o1);
        const uint32_t bits = o0 ^ o1;
        float f = __uint_as_float((bits >> 9) | 0x3f800000u) - 1.0f;
        float u = fmaxf(f, 1.17549435e-38f);
        float g = -logf(-logf(u));
        float val = acc[a][q][j] + bias[v] + g;
        uint32_t uv = __float_as_uint(val);
        uv = (uv & 0x80000000u) ? ~uv : (uv | 0x80000000u);
        unsigned long long pk =
            ((unsigned long long)uv << 32) |
            (unsigned long long)(0xFFFFFFFFu - (uint32_t)v);
        best = (pk > best) ? pk : best;
      }
#pragma unroll
    for (int m = 1; m < 16; m <<= 1) {
      unsigned long long o = shflx64(best, m);
      best = (o > best) ? o : best;
    }
    if (tx == 0) part[(size_t)r * 250 + blockIdx.x] = best;
  }
}

// ---------------------------------------------------------------------------
// k_gates: per 16-row x 128-col(permuted) block: token reduce + embed gather +
// full-K gates GEMM + fused LSTM update. grid (16 rowgrps, 8 colgrps), 256 thr.
// Wp row 4e+g = [W_ih|W_hh] row g*256+e -> each col quad = (i,f,g,o) of unit e.
// ---------------------------------------------------------------------------
__global__ __launch_bounds__(256) void k_gates(
    const unsigned long long* __restrict__ part,  // [256][250]
    const float* __restrict__ emb,    // [32000][256]
    const float* __restrict__ h,      // h_cur [256][256]
    const float* __restrict__ Wp,     // [1024][512]
    const float* __restrict__ bcatp,  // [1024]
    float* __restrict__ c,            // [256][256]
    float* __restrict__ hn,           // h_nxt [256][256]
    int* __restrict__ out, int t)
{
  __shared__ float At[16][520];                 // [row][k], x|h
  __shared__ float Bt[16][132];                 // [k][col]
  __shared__ unsigned long long red2[16][17];
  __shared__ int tok_s[16];
  const int tid = threadIdx.x;
  const int tx = tid & 31, ty = tid >> 5;       // cols 4*tx (128), rows 2*ty (16)
  const int R0 = blockIdx.x * 16;
  const int C0 = blockIdx.y * 128;
  float acc[2][4] = {};

  // phase A: token reduce for 16 rows
  {
    const int rw = tid >> 4, il = tid & 15;
    unsigned long long b = 0ull;
    for (int i = il; i < 250; i += 16) {
      unsigned long long x = part[(size_t)(R0 + rw) * 250 + i];
      b = (x > b) ? x : b;
    }
    red2[rw][il] = b;
  }
  __syncthreads();
  if (tid < 16) {
    unsigned long long b = 0ull;
#pragma unroll
    for (int i = 0; i < 16; i++) {
      unsigned long long x = red2[tid][i];
      b = (x > b) ? x : b;
    }
    int tok = (int)(0xFFFFFFFFu - (uint32_t)(b & 0xFFFFFFFFu));
    tok_s[tid] = tok;
    if (blockIdx.y == 0) out[(size_t)(R0 + tid) * STEPS + t] = tok;
  }
  __syncthreads();

  // phase B: stage At[r][0..511] = [emb[tok_r] | h[R0+r]]
#pragma unroll
  for (int i = 0; i < 8; i++) {
    int f = tid + 256 * i;            // 0..2047
    int r = f >> 7, k4 = f & 127;
    const float* src = (k4 < 64)
        ? (emb + (size_t)tok_s[r] * 256 + 4 * k4)
        : (h + (size_t)(R0 + r) * 256 + 4 * (k4 - 64));
    *(float4*)&At[r][4 * k4] = *(const float4*)src;
  }

  // stage Bt chunk 0
#pragma unroll
  for (int i = 0; i < 2; i++) {
    int f = tid + 256 * i;            // 0..511
    int cc = f >> 2, kq = f & 3;
    float4 w = *(const float4*)(Wp + (size_t)(C0 + cc) * 512 + 4 * kq);
    Bt[4 * kq + 0][cc] = w.x; Bt[4 * kq + 1][cc] = w.y;
    Bt[4 * kq + 2][cc] = w.z; Bt[4 * kq + 3][cc] = w.w;
  }
  __syncthreads();

  // K-loop: 32 chunks of 16, register-prefetch next Wp chunk
  for (int ch = 0; ch < 32; ch++) {
    float4 pf[2];
    if (ch < 31) {
#pragma unroll
      for (int i = 0; i < 2; i++) {
        int f = tid + 256 * i;
        int cc = f >> 2, kq = f & 3;
        pf[i] = *(const float4*)(Wp + (size_t)(C0 + cc) * 512 + (ch + 1) * 16 + 4 * kq);
      }
    }
#pragma unroll
    for (int k = 0; k < 16; k++) {
      float af0 = At[2 * ty + 0][16 * ch + k];
      float af1 = At[2 * ty + 1][16 * ch + k];
      float4 bf = *(const float4*)&Bt[k][4 * tx];
      acc[0][0] = fmaf(af0, bf.x, acc[0][0]);
      acc[0][1] = fmaf(af0, bf.y, acc[0][1]);
      acc[0][2] = fmaf(af0, bf.z, acc[0][2]);
      acc[0][3] = fmaf(af0, bf.w, acc[0][3]);
      acc[1][0] = fmaf(af1, bf.x, acc[1][0]);
      acc[1][1] = fmaf(af1, bf.y, acc[1][1]);
      acc[1][2] = fmaf(af1, bf.z, acc[1][2]);
      acc[1][3] = fmaf(af1, bf.w, acc[1][3]);
    }
    __syncthreads();
    if (ch < 31) {
#pragma unroll
      for (int i = 0; i < 2; i++) {
        int f = tid + 256 * i;
        int cc = f >> 2, kq = f & 3;
        Bt[4 * kq + 0][cc] = pf[i].x; Bt[4 * kq + 1][cc] = pf[i].y;
        Bt[4 * kq + 2][cc] = pf[i].z; Bt[4 * kq + 3][cc] = pf[i].w;
      }
    }
    __syncthreads();
  }

  // epilogue: LSTM update for unit e = C0/4 + tx, rows R0+2ty{,+1}
  const int e = (C0 >> 2) + tx;
  float4 bb = *(const float4*)(bcatp + C0 + 4 * tx);
#pragma unroll
  for (int a = 0; a < 2; a++) {
    const int r = R0 + 2 * ty + a;
    float gi = acc[a][0] + bb.x;
    float gf = acc[a][1] + bb.y;
    float gg = acc[a][2] + bb.z;
    float go = acc[a][3] + bb.w;
    float si = 1.0f / (1.0f + expf(-gi));
    float sf = 1.0f / (1.0f + expf(-gf));
    float so = 1.0f / (1.0f + expf(-go));
    float cv = sf * c[(size_t)r * 256 + e] + si * tanhf(gg);
    c[(size_t)r * 256 + e] = cv;
    hn[(size_t)r * 256 + e] = so * tanhf(cv);
  }
}

__global__ __launch_bounds__(256) void k_init(
    float* __restrict__ h, float* __restrict__ c,
    const float* __restrict__ init_h)
{
  const int n = blockIdx.x, e = threadIdx.x;
  const float v = init_h[e];
  h[(size_t)n * 256 + e] = v;
  c[(size_t)n * 256 + e] = v;
}

// Wp[4e+g][:] = [W_ih | W_hh][g*256+e][:]; bcatp[4e+g] = b_ih+b_hh
__global__ __launch_bounds__(256) void k_prep(
    float* __restrict__ Wp, float* __restrict__ bcatp,
    const float* __restrict__ W_ih, const float* __restrict__ W_hh,
    const float* __restrict__ b_ih, const float* __restrict__ b_hh)
{
  const int q = blockIdx.x, k = threadIdx.x;
  const int e = q >> 2, g = q & 3;
  const int src = g * 256 + e;
  Wp[(size_t)q * 512 + k]       = W_ih[(size_t)src * 256 + k];
  Wp[(size_t)q * 512 + 256 + k] = W_hh[(size_t)src * 256 + k];
  if (k == 0) bcatp[q] = b_ih[src] + b_hh[src];
}

extern "C" void kernel_launch(void* const* d_in, const int* in_sizes, int n_in,
                              void* d_out, int out_size, void* d_ws, size_t ws_size,
                              hipStream_t stream) {
  const float* init_h      = (const float*)d_in[2];
  const float* token_embed = (const float*)d_in[3];
  const float* W_ih        = (const float*)d_in[4];
  const float* W_hh        = (const float*)d_in[5];
  const float* b_ih        = (const float*)d_in[6];
  const float* b_hh        = (const float*)d_in[7];
  const float* W1          = (const float*)d_in[8];
  const float* b1          = (const float*)d_in[9];
  const float* W2          = (const float*)d_in[10];
  const float* b2          = (const float*)d_in[11];
  int* out = (int*)d_out;

  // workspace carve (16B-aligned)
  char* ws = (char*)d_ws;
  float* h0    = (float*)(ws + 0);        // 256 KB [256][256]
  float* h1    = (float*)(ws + 262144);   // 256 KB [256][256]
  float* c     = (float*)(ws + 524288);   // 256 KB [256][256]
  float* Wp    = (float*)(ws + 786432);   //   2 MB [1024][512]
  float* bcatp = (float*)(ws + 2883584);  //   4 KB [1024]
  unsigned long long* part = (unsigned long long*)(ws + 2887680); // 500 KB
  float* hidden = (float*)(ws + 3399680); // 512 KB [256][512]
  // total 3,923,968 B

  // host JAX key schedule (partitionable split, verified round 2)
  uint32_t k0[STEPS], k1[STEPS];
  for (uint32_t t = 0; t < STEPS; t++) tf2x32(0u, 42u, 0u, t, k0[t], k1[t]);

  k_init<<<NS, 256, 0, stream>>>(h0, c, init_h);
  k_prep<<<1024, 256, 0, stream>>>(Wp, bcatp, W_ih, W_hh, b_ih, b_hh);
  k_hidden<<<dim3(8, 4), 256, 0, stream>>>(h0, W1, b1, hidden);

  for (int t = 0; t < STEPS; t++) {
    float* hc = (t & 1) ? h1 : h0;
    float* hx = (t & 1) ? h0 : h1;
    k_logits<<<250, 512, 0, stream>>>(hidden, W2, b2, part, k0[t], k1[t]);
    k_gates<<<dim3(16, 8), 256, 0, stream>>>(part, token_embed, hc, Wp, bcatp,
                                             c, hx, out, t);
    k_hidden<<<dim3(8, 4), 256, 0, stream>>>(hx, W1, b1, hidden);
  }
}